// Round 1
// baseline (879.500 us; speedup 1.0000x reference)
//
#include <hip/hip_runtime.h>

#define SEQ 512
#define BATCH 256
#define INDIM 256
#define MLP 128
#define M_ROWS (SEQ * BATCH)        // 131072
#define PRE_STRIDE 136              // 128 mlp-pre + 4 gate-pre + 4 pad
#define AUX_OFF ((size_t)M_ROWS * PRE_STRIDE)  // in floats

// ---------------------------------------------------------------------------
// Kernel 1: prep — column sums of the recurrent halves of W1 and gate weights.
// aux[0..127]  = s1[j]   = sum_k W1[256+k][j]
// aux[128..131]= sf,si,sg,so = sum_k W{f,i,g,o}[256+k]
// aux[132..135]= bf,bi,bg,bo   (packed gate biases; unused by rec, kept anyway)
// ---------------------------------------------------------------------------
__global__ __launch_bounds__(256) void prep_kernel(
    const float* __restrict__ W1,
    const float* __restrict__ Wf, const float* __restrict__ Wi,
    const float* __restrict__ Wg, const float* __restrict__ Wo,
    const float* __restrict__ bf, const float* __restrict__ bi,
    const float* __restrict__ bg, const float* __restrict__ bo,
    float* __restrict__ aux) {
  const int tid = threadIdx.x;
  if (tid < 128) {
    float s = 0.f;
    for (int k = 0; k < 256; ++k) s += W1[(size_t)(256 + k) * 128 + tid];
    aux[tid] = s;
  } else if (tid < 132) {
    const int g = tid - 128;
    const float* w = (g == 0) ? Wf : (g == 1) ? Wi : (g == 2) ? Wg : Wo;
    float s = 0.f;
    for (int k = 0; k < 256; ++k) s += w[256 + k];
    aux[128 + g] = s;
  } else if (tid < 136) {
    const int g = tid - 132;
    const float* bp = (g == 0) ? bf : (g == 1) ? bi : (g == 2) ? bg : bo;
    aux[132 + g] = bp[0];
  }
}

// ---------------------------------------------------------------------------
// Kernel 2: big fp32 GEMM over all (t,b) rows.
// PRE[row][0..127]  = x_row . W1[:256,:] + b1          (mlp pre-activation)
// PRE[row][128..131]= x_row . W{f,i,g,o}[:256] + bias  (gate pre-activations)
// BM=128 rows/block, BN=128 cols, BK=16; 256 threads; 8x8 accs/thread.
// ---------------------------------------------------------------------------
#define BK 16
#define LDX 132  // padded LDS row stride (words)

__global__ __launch_bounds__(256) void gemm_kernel(
    const float* __restrict__ X,    // [M_ROWS][256]
    const float* __restrict__ W1,   // [512][128] (only rows 0..255 used here)
    const float* __restrict__ b1p,  // [128]
    const float* __restrict__ Wf, const float* __restrict__ Wi,
    const float* __restrict__ Wg, const float* __restrict__ Wo,
    const float* __restrict__ bfp, const float* __restrict__ bip,
    const float* __restrict__ bgp, const float* __restrict__ bop,
    float* __restrict__ PRE) {
  __shared__ __align__(16) float Xs[BK * LDX];   // [kk][row], row-padded
  __shared__ __align__(16) float Ws[BK * LDX];   // [kk][col]
  __shared__ float Wgs[BK * 4];                  // [kk][gate]

  const int tid = threadIdx.x;
  const int blk = blockIdx.x;
  const int tx = tid & 15, ty = tid >> 4;       // 16x16 thread grid
  const int r_st = tid >> 1, kh = (tid & 1) * 8; // X staging role
  const int wk = tid >> 4, wn = (tid & 15) * 8;  // W staging role
  const int r2 = tid >> 1, gp = (tid & 1) * 2;   // gate compute role

  const size_t rowbase = (size_t)blk * 128;

  float acc[8][8] = {};
  float ga = 0.f, gb = 0.f;

  for (int kc = 0; kc < 256; kc += BK) {
    // global loads for staging
    const float4 xa = *(const float4*)&X[(rowbase + r_st) * 256 + kc + kh];
    const float4 xb = *(const float4*)&X[(rowbase + r_st) * 256 + kc + kh + 4];
    const float4 wa = *(const float4*)&W1[(size_t)(kc + wk) * 128 + wn];
    const float4 wb = *(const float4*)&W1[(size_t)(kc + wk) * 128 + wn + 4];
    float wgv = 0.f;
    if (tid < 64) {
      const int kk = tid >> 2, g = tid & 3;
      const float* w = (g == 0) ? Wf : (g == 1) ? Wi : (g == 2) ? Wg : Wo;
      wgv = w[kc + kk];
    }
    __syncthreads();  // previous chunk's compute must be done before overwrite
    // X tile transposed to [kk][row]
    Xs[(kh + 0) * LDX + r_st] = xa.x;
    Xs[(kh + 1) * LDX + r_st] = xa.y;
    Xs[(kh + 2) * LDX + r_st] = xa.z;
    Xs[(kh + 3) * LDX + r_st] = xa.w;
    Xs[(kh + 4) * LDX + r_st] = xb.x;
    Xs[(kh + 5) * LDX + r_st] = xb.y;
    Xs[(kh + 6) * LDX + r_st] = xb.z;
    Xs[(kh + 7) * LDX + r_st] = xb.w;
    *(float4*)&Ws[wk * LDX + wn] = wa;
    *(float4*)&Ws[wk * LDX + wn + 4] = wb;
    if (tid < 64) Wgs[tid] = wgv;  // layout [kk][g] == tid
    __syncthreads();

#pragma unroll
    for (int kk = 0; kk < BK; ++kk) {
      const float4 a0 = *(const float4*)&Xs[kk * LDX + ty * 8];
      const float4 a1 = *(const float4*)&Xs[kk * LDX + ty * 8 + 4];
      const float4 c0 = *(const float4*)&Ws[kk * LDX + tx * 8];
      const float4 c1 = *(const float4*)&Ws[kk * LDX + tx * 8 + 4];
      const float av[8] = {a0.x, a0.y, a0.z, a0.w, a1.x, a1.y, a1.z, a1.w};
      const float bv[8] = {c0.x, c0.y, c0.z, c0.w, c1.x, c1.y, c1.z, c1.w};
#pragma unroll
      for (int i = 0; i < 8; ++i)
#pragma unroll
        for (int j = 0; j < 8; ++j)
          acc[i][j] = fmaf(av[i], bv[j], acc[i][j]);
      // fused gate columns: thread covers (row r2, gates gp, gp+1)
      const float xv = Xs[kk * LDX + r2];
      ga = fmaf(xv, Wgs[kk * 4 + gp], ga);
      gb = fmaf(xv, Wgs[kk * 4 + gp + 1], gb);
    }
  }

  // epilogue: add b1 and store mlp pre-activations
  float bias[8];
  {
    const float4 u0 = *(const float4*)&b1p[tx * 8];
    const float4 u1 = *(const float4*)&b1p[tx * 8 + 4];
    bias[0] = u0.x; bias[1] = u0.y; bias[2] = u0.z; bias[3] = u0.w;
    bias[4] = u1.x; bias[5] = u1.y; bias[6] = u1.z; bias[7] = u1.w;
  }
#pragma unroll
  for (int i = 0; i < 8; ++i) {
    const size_t row = rowbase + ty * 8 + i;
    float4 o0, o1;
    o0.x = acc[i][0] + bias[0]; o0.y = acc[i][1] + bias[1];
    o0.z = acc[i][2] + bias[2]; o0.w = acc[i][3] + bias[3];
    o1.x = acc[i][4] + bias[4]; o1.y = acc[i][5] + bias[5];
    o1.z = acc[i][6] + bias[6]; o1.w = acc[i][7] + bias[7];
    *(float4*)&PRE[row * PRE_STRIDE + tx * 8] = o0;
    *(float4*)&PRE[row * PRE_STRIDE + tx * 8 + 4] = o1;
  }
  // gate epilogue
  {
    const float bf0 = bfp[0], bi0 = bip[0], bg0 = bgp[0], bo0 = bop[0];
    const float ab = (gp == 0) ? bf0 : bg0;
    const float bb = (gp == 0) ? bi0 : bo0;
    const size_t row = rowbase + r2;
    float2 og;
    og.x = ga + ab; og.y = gb + bb;
    *(float2*)&PRE[row * PRE_STRIDE + 128 + gp] = og;
  }
}

// ---------------------------------------------------------------------------
// Kernel 3: serial recurrence. One wave (64 lanes) per batch element.
// ---------------------------------------------------------------------------
__device__ __forceinline__ float sigmoid_f(float x) {
  return __fdividef(1.0f, 1.0f + __expf(-x));
}
__device__ __forceinline__ float tanh_f(float x) {
  const float e = __expf(-2.0f * x);
  return __fdividef(1.0f - e, 1.0f + e);
}
__device__ __forceinline__ float qgate_f(const float* c) {
  float p = c[0], s = c[0];
#pragma unroll
  for (int k = 1; k < 8; ++k) { p *= c[k]; s += p; }
  return s * 0.125f;
}

__global__ __launch_bounds__(64) void rec_kernel(
    const float* __restrict__ PRE, const float* __restrict__ W2,
    const float* __restrict__ b2, const float* __restrict__ aux,
    float* __restrict__ out) {
  __shared__ __align__(16) float h1s[128];
  __shared__ __align__(16) float csh[32];

  const int l = threadIdx.x;
  const int b = blockIdx.x;
  const int m = l & 31, half = l >> 5;

  // W2 fragment: lane (m, half) holds W2[half*64+u][m], u=0..63
  float w2r[64];
#pragma unroll
  for (int u = 0; u < 64; ++u) w2r[u] = W2[(size_t)(half * 64 + u) * 32 + m];
  const float b2v = b2[m];
  const float2 s1 = *(const float2*)&aux[2 * l];
  const float4 sg = *(const float4*)&aux[128];  // sf, si, sg, so

  float h = 0.f, c = 0.f;

  const float* pr0 = PRE + (size_t)b * PRE_STRIDE;           // t stride below
  const size_t tstride = (size_t)BATCH * PRE_STRIDE;

  // depth-3 prefetch pipeline
  float2 p0 = *(const float2*)(pr0 + 0 * tstride + 2 * l);
  float4 g0 = *(const float4*)(pr0 + 0 * tstride + 128);
  float2 p1 = *(const float2*)(pr0 + 1 * tstride + 2 * l);
  float4 g1 = *(const float4*)(pr0 + 1 * tstride + 128);
  float2 p2 = *(const float2*)(pr0 + 2 * tstride + 2 * l);
  float4 g2 = *(const float4*)(pr0 + 2 * tstride + 128);

  for (int t = 0; t < SEQ; ++t) {
    // h1 = relu(pre + h*s1)   (b1 already folded into PRE)
    const float h10 = fmaxf(fmaf(h, s1.x, p0.x), 0.f);
    const float h11 = fmaxf(fmaf(h, s1.y, p0.y), 0.f);
    // classical gate pre-activations
    const float zf = fmaf(h, sg.x, g0.x);
    const float zi = fmaf(h, sg.y, g0.y);
    const float zg = fmaf(h, sg.z, g0.z);
    const float zo = fmaf(h, sg.w, g0.w);
    // rotate prefetch (distance 3)
    p0 = p1; g0 = g1; p1 = p2; g1 = g2;
    const int tn = (t + 3 < SEQ) ? (t + 3) : (SEQ - 1);
    p2 = *(const float2*)(pr0 + (size_t)tn * tstride + 2 * l);
    g2 = *(const float4*)(pr0 + (size_t)tn * tstride + 128);

    // broadcast h1 through LDS
    ((float2*)h1s)[l] = make_float2(h10, h11);
    __syncthreads();

    // q[m] = sum_j h1[j] * W2[j][m]  — each (m,half) lane sums 64 j's
    float q0 = 0.f, q1 = 0.f, q2 = 0.f, q3 = 0.f;
    const float4* hv4 = (const float4*)&h1s[half * 64];
#pragma unroll
    for (int jj = 0; jj < 16; ++jj) {
      const float4 hv = hv4[jj];
      q0 = fmaf(hv.x, w2r[4 * jj + 0], q0);
      q1 = fmaf(hv.y, w2r[4 * jj + 1], q1);
      q2 = fmaf(hv.z, w2r[4 * jj + 2], q2);
      q3 = fmaf(hv.w, w2r[4 * jj + 3], q3);
    }
    const float qh = (q0 + q1) + (q2 + q3);
    const float theta = qh + __shfl_xor(qh, 32, 64) + b2v;
    const float cv = __cosf(theta);
    if (l < 32) csh[m] = cv;
    __syncthreads();

    // every lane reads all 32 cos values and does the 4 qgates serially
    float cc[32];
#pragma unroll
    for (int u = 0; u < 8; ++u) {
      const float4 v = ((const float4*)csh)[u];
      cc[4 * u + 0] = v.x; cc[4 * u + 1] = v.y;
      cc[4 * u + 2] = v.z; cc[4 * u + 3] = v.w;
    }
    const float qf = qgate_f(cc + 0);
    const float qi = qgate_f(cc + 8);
    const float qg = qgate_f(cc + 16);
    const float qo = qgate_f(cc + 24);

    const float f  = 0.5f * (sigmoid_f(zf) + sigmoid_f(qf));
    const float ii = 0.5f * (sigmoid_f(zi) + sigmoid_f(qi));
    const float gg = 0.5f * (tanh_f(zg) + tanh_f(qg));
    const float oo = 0.5f * (sigmoid_f(zo) + sigmoid_f(qo));

    c = fmaf(f, c, ii * gg);
    h = oo * tanh_f(c);

    float4 hv4o; hv4o.x = h; hv4o.y = h; hv4o.z = h; hv4o.w = h;
    *(float4*)(out + ((size_t)t * BATCH + b) * 256 + 4 * l) = hv4o;
  }

  // final (hx, cx) outputs
  float4 hq; hq.x = h; hq.y = h; hq.z = h; hq.w = h;
  float4 cq; cq.x = c; cq.y = c; cq.z = c; cq.w = c;
  *(float4*)(out + (size_t)SEQ * BATCH * 256 + (size_t)b * 256 + 4 * l) = hq;
  *(float4*)(out + (size_t)SEQ * BATCH * 256 + (size_t)BATCH * 256 +
             (size_t)b * 256 + 4 * l) = cq;
}

// ---------------------------------------------------------------------------
extern "C" void kernel_launch(void* const* d_in, const int* in_sizes, int n_in,
                              void* d_out, int out_size, void* d_ws,
                              size_t ws_size, hipStream_t stream) {
  const float* X  = (const float*)d_in[0];
  const float* W1 = (const float*)d_in[1];
  const float* b1 = (const float*)d_in[2];
  const float* W2 = (const float*)d_in[3];
  const float* b2 = (const float*)d_in[4];
  const float* Wf = (const float*)d_in[5];
  const float* bf = (const float*)d_in[6];
  const float* Wi = (const float*)d_in[7];
  const float* bi = (const float*)d_in[8];
  const float* Wg = (const float*)d_in[9];
  const float* bg = (const float*)d_in[10];
  const float* Wo = (const float*)d_in[11];
  const float* bo = (const float*)d_in[12];

  float* ws  = (float*)d_ws;
  float* PRE = ws;
  float* aux = ws + AUX_OFF;
  float* out = (float*)d_out;

  prep_kernel<<<1, 256, 0, stream>>>(W1, Wf, Wi, Wg, Wo, bf, bi, bg, bo, aux);
  gemm_kernel<<<M_ROWS / 128, 256, 0, stream>>>(X, W1, b1, Wf, Wi, Wg, Wo,
                                                bf, bi, bg, bo, PRE);
  rec_kernel<<<BATCH, 64, 0, stream>>>(PRE, W2, b2, aux, out);
}